// Round 1
// baseline (297.376 us; speedup 1.0000x reference)
//
#include <hip/hip_runtime.h>
#include <math.h>

#define D_MODEL 1024
#define D_STATE 128
#define SEQ_LEN 4096
#define BATCH 4
#define NTOK (BATCH * SEQ_LEN)      // 16384
#define LN_EPS 1e-3f
#define NCHUNK 128
#define LCHUNK (SEQ_LEN / NCHUNK)   // 32

typedef __attribute__((ext_vector_type(8))) short bf16x8;
typedef __attribute__((ext_vector_type(4))) float f32x4;

__device__ __forceinline__ short f2bf(float f) {
    union { float f; unsigned u; } v; v.f = f;
    unsigned r = v.u + 0x7FFFu + ((v.u >> 16) & 1u);   // RNE
    return (short)(r >> 16);
}
__device__ __forceinline__ float bf2f(short s) {
    union { unsigned u; float f; } v; v.u = ((unsigned)(unsigned short)s) << 16;
    return v.f;
}

// ---------------- LayerNorm -> bf16 output ----------------
__global__ __launch_bounds__(256) void ln_kernel(const float* __restrict__ x,
                                                 const float* __restrict__ gamma,
                                                 const float* __restrict__ beta,
                                                 short* __restrict__ xn_bf) {
    int row = blockIdx.x;
    const float4* xr = (const float4*)(x + (size_t)row * D_MODEL);
    float4 v = xr[threadIdx.x];
    float s1 = v.x + v.y + v.z + v.w;
    float s2 = v.x * v.x + v.y * v.y + v.z * v.z + v.w * v.w;
    for (int off = 32; off; off >>= 1) {
        s1 += __shfl_down(s1, off);
        s2 += __shfl_down(s2, off);
    }
    __shared__ float ls1[4], ls2[4];
    int wid = threadIdx.x >> 6, lane = threadIdx.x & 63;
    if (lane == 0) { ls1[wid] = s1; ls2[wid] = s2; }
    __syncthreads();
    s1 = ls1[0] + ls1[1] + ls1[2] + ls1[3];
    s2 = ls2[0] + ls2[1] + ls2[2] + ls2[3];
    float mu = s1 * (1.0f / D_MODEL);
    float var = s2 * (1.0f / D_MODEL) - mu * mu;
    float r = rsqrtf(var + LN_EPS);
    float4 g = ((const float4*)gamma)[threadIdx.x];
    float4 b = ((const float4*)beta)[threadIdx.x];
    short4 o;
    o.x = f2bf((v.x - mu) * r * g.x + b.x);
    o.y = f2bf((v.y - mu) * r * g.y + b.y);
    o.z = f2bf((v.z - mu) * r * g.z + b.z);
    o.w = f2bf((v.w - mu) * r * g.w + b.w);
    ((short4*)(xn_bf + (size_t)row * D_MODEL))[threadIdx.x] = o;
}

// ---------------- fused weight prep: all transposes + bias3 in ONE launch ----
__global__ __launch_bounds__(256) void prep_kernel(
    const float* __restrict__ W_in, const float* __restrict__ W_xs,
    const float* __restrict__ W_B, const float* __restrict__ W_C,
    const float* __restrict__ W_so, const float* __restrict__ W_out,
    const float* __restrict__ bB, const float* __restrict__ bC,
    short* __restrict__ W_inT, short* __restrict__ W3T,
    short* __restrict__ W_soT, short* __restrict__ W_outT,
    float* __restrict__ bias3) {
    int blk = blockIdx.x;
    const float* in; short* out; int K, N, tile;
    if (blk < 1024)      { in = W_in;  out = W_inT;           K = 1024; N = 1024; tile = blk; }
    else if (blk < 1152) { in = W_xs;  out = W3T;             K = 1024; N = 128;  tile = blk - 1024; }
    else if (blk < 1280) { in = W_B;   out = W3T + 128*1024;  K = 1024; N = 128;  tile = blk - 1152; }
    else if (blk < 1408) { in = W_C;   out = W3T + 256*1024;  K = 1024; N = 128;  tile = blk - 1280; }
    else if (blk < 1536) { in = W_so;  out = W_soT;           K = 128;  N = 1024; tile = blk - 1408; }
    else if (blk < 2560) { in = W_out; out = W_outT;          K = 1024; N = 1024; tile = blk - 1536; }
    else {
        int t = threadIdx.y * 32 + threadIdx.x;
        for (int n = t; n < 384; n += 256)
            bias3[n] = (n < 128) ? 0.f : ((n < 256) ? bB[n - 128] : bC[n - 256]);
        return;
    }
    __shared__ float t32[32][33];
    int ntiles = N / 32;
    int nb = (tile % ntiles) * 32, kb = (tile / ntiles) * 32;
    int tx = threadIdx.x, ty = threadIdx.y;   // 32 x 8
#pragma unroll
    for (int i = 0; i < 4; ++i)
        t32[ty + 8 * i][tx] = in[(size_t)(kb + ty + 8 * i) * N + nb + tx];
    __syncthreads();
#pragma unroll
    for (int i = 0; i < 4; ++i)
        out[(size_t)(nb + ty + 8 * i) * K + kb + tx] = f2bf(t32[tx][ty + 8 * i]);
}

// ---------------- bf16 MFMA GEMM: BK=64, XOR-swizzled LDS, XCD swizzle ------
// (retained for the N=384 projection GEMM and the K=128 W_so GEMM)
template<int HAS_BIAS, int HAS_ADD, int ADD_BF, int HAS_SCALE, int OUT_F32, int OUT_BF, int SWZ>
__global__ __launch_bounds__(256, 4) void gemm_bf16(
    const short* __restrict__ A, const short* __restrict__ BT,
    const float* __restrict__ bias,
    const float* __restrict__ addf, const short* __restrict__ addb,
    const float* __restrict__ addscale,
    float* __restrict__ Cf, short* __restrict__ Cbf,
    int Mt, int Nt, int K) {
    __shared__ short As[128 * 64];   // 16 KiB
    __shared__ short Bs[128 * 64];   // 16 KiB
    int p = blockIdx.x;
    int mtile, ntile;
    if (SWZ) {
        int k = p & 7, q = p >> 3;
        ntile = q & 7;
        mtile = k + 8 * (q >> 3);
    } else {
        mtile = p % Mt;
        ntile = p / Mt;
    }
    int m0 = mtile * 128, n0 = ntile * 128;
    int N = Nt * 128;
    int tid = threadIdx.x;
    int lane = tid & 63;
    int w = tid >> 6;
    int quad = lane >> 4, r16 = lane & 15;
    int wm = (w & 1) * 64, wn = (w >> 1) * 64;

    f32x4 acc[4][4] = {};

    for (int k0 = 0; k0 < K; k0 += 64) {
#pragma unroll
        for (int it = 0; it < 4; ++it) {
            int seg = it * 256 + tid;          // 0..1023
            int row = seg >> 3, slot = seg & 7;
            int kc8 = slot ^ (row & 7);
            const short* gp = A + (size_t)(m0 + row) * K + k0 + kc8 * 8;
            __builtin_amdgcn_global_load_lds(
                (const __attribute__((address_space(1))) unsigned*)gp,
                (__attribute__((address_space(3))) unsigned*)(As + seg * 8), 16, 0, 0);
        }
#pragma unroll
        for (int it = 0; it < 4; ++it) {
            int seg = it * 256 + tid;
            int row = seg >> 3, slot = seg & 7;
            int kc8 = slot ^ (row & 7);
            const short* gp = BT + (size_t)(n0 + row) * K + k0 + kc8 * 8;
            __builtin_amdgcn_global_load_lds(
                (const __attribute__((address_space(1))) unsigned*)gp,
                (__attribute__((address_space(3))) unsigned*)(Bs + seg * 8), 16, 0, 0);
        }
        __syncthreads();

        const short* abase = As + (wm + r16) * 64;
        const short* bbase = Bs + (wn + r16) * 64;
        int sw = r16 & 7;
#pragma unroll
        for (int kk = 0; kk < 2; ++kk) {
            int phys = ((quad + 4 * kk) ^ sw) * 8;
            bf16x8 af[4], bfr[4];
#pragma unroll
            for (int i = 0; i < 4; ++i) af[i] = *(const bf16x8*)(abase + i * 16 * 64 + phys);
#pragma unroll
            for (int j = 0; j < 4; ++j) bfr[j] = *(const bf16x8*)(bbase + j * 16 * 64 + phys);
#pragma unroll
            for (int i = 0; i < 4; ++i)
#pragma unroll
                for (int j = 0; j < 4; ++j)
                    acc[i][j] = __builtin_amdgcn_mfma_f32_16x16x32_bf16(af[i], bfr[j], acc[i][j], 0, 0, 0);
        }
        __syncthreads();
    }

#pragma unroll
    for (int i = 0; i < 4; ++i) {
#pragma unroll
        for (int j = 0; j < 4; ++j) {
            int col = n0 + wn + j * 16 + r16;
            float bv = HAS_BIAS ? bias[col] : 0.f;
            float sc = HAS_SCALE ? addscale[col] : 1.f;
#pragma unroll
            for (int pr = 0; pr < 4; ++pr) {
                int row = m0 + wm + i * 16 + quad * 4 + pr;
                float v = acc[i][j][pr] + bv;
                if (HAS_ADD) {
                    float av = ADD_BF ? bf2f(addb[(size_t)row * N + col])
                                      : addf[(size_t)row * N + col];
                    v += sc * av;
                }
                if (OUT_F32) Cf[(size_t)row * N + col] = v;
                if (OUT_BF) Cbf[(size_t)row * N + col] = f2bf(v);
            }
        }
    }
}

// ---------------- 256x256 counted-vmcnt phase-pipelined bf16 GEMM ----------
// T1 (XCD swizzle) + swizzled LDS + T3/T4 (4-phase/K-tile, counted vmcnt,
// never drained in main loop) + T5 (setprio around MFMA clusters).
// LDS 128 KiB: [2 tile-buf][2 K-chunk] x 256 rows x 32 cols x bf16, A and B.
// Stage unit = one (buf, chunk, matrix) block = 16 KiB = 2 loads/thread.
// Per-thread wait arithmetic: loads issued - loads needed = 8 in steady state.
#define WAITV8 asm volatile("s_waitcnt vmcnt(8)" ::: "memory")
#define WAITV4 asm volatile("s_waitcnt vmcnt(4)" ::: "memory")
#define WAITV0 asm volatile("s_waitcnt vmcnt(0)" ::: "memory")
#define SBARF  do { __builtin_amdgcn_s_barrier(); asm volatile("" ::: "memory"); } while (0)

template<int HAS_BIAS, int HAS_ADD, int OUT_F32, int OUT_BF, int SWZ>
__global__ __launch_bounds__(512, 2) void gemm256(
    const short* __restrict__ A, const short* __restrict__ BT,
    const float* __restrict__ bias, const float* __restrict__ addf,
    float* __restrict__ Cf, short* __restrict__ Cbf,
    int Mt, int Nt, int K) {
    __shared__ short LA[2][2][8192];   // 64 KiB
    __shared__ short LB[2][2][8192];   // 64 KiB
    int p = blockIdx.x;
    int mtile, ntile;
    if (SWZ) {                 // bijective: grid = Mt*Nt, Mt multiple of 8
        int xcd = p & 7, q = p >> 3;
        ntile = q % Nt;
        mtile = xcd + 8 * (q / Nt);
    } else {
        mtile = p % Mt;
        ntile = p / Mt;
    }
    int m0 = mtile * 256, n0 = ntile * 256;
    int N = Nt * 256;
    int tid = threadIdx.x;
    int lane = tid & 63, w = tid >> 6;
    int quad = lane >> 4, r16 = lane & 15;
    int wm = w & 1, wn = w >> 1;       // 2 M-halves x 4 N-quarters
    int nt = K >> 6;                   // K-tiles of 64

    f32x4 acc[8][4] = {};

    // stage one unit: tile TU, K-chunk KK (0/1), matrix ISB (0=A,1=B).
    // LDS dest linear in tid; global source carries the inverse swizzle.
#define STG(TU, KK, ISB) do { \
        const short* g_ = (ISB) ? BT : A; \
        int rb_ = (ISB) ? n0 : m0; \
        short* l_ = (ISB) ? &LB[(TU) & 1][KK][0] : &LA[(TU) & 1][KK][0]; \
        _Pragma("unroll") \
        for (int r_ = 0; r_ < 2; ++r_) { \
            int seg_ = r_ * 512 + tid; \
            int row_ = seg_ >> 2, sl_ = seg_ & 3; \
            int kc_ = sl_ ^ ((row_ >> 1) & 3); \
            const short* gp_ = g_ + (size_t)(rb_ + row_) * K + (TU) * 64 + (KK) * 32 + kc_ * 8; \
            __builtin_amdgcn_global_load_lds( \
                (const __attribute__((address_space(1))) unsigned*)gp_, \
                (__attribute__((address_space(3))) unsigned*)(&l_[seg_ * 8]), 16, 0, 0); \
        } \
    } while (0)

#define PH_LOADB(Bb) { _Pragma("unroll") for (int j_ = 0; j_ < 4; ++j_) \
        bf[j_] = *(const bf16x8*)((Bb) + j_ * 512 + ph4); }
#define PH_LOADA(Ab, IH) { _Pragma("unroll") for (int i_ = 0; i_ < 4; ++i_) \
        af[i_] = *(const bf16x8*)((Ab) + (i_ + 4 * (IH)) * 512 + ph4); }
#define PH_MFMA(IH) { __builtin_amdgcn_s_setprio(1); \
        _Pragma("unroll") for (int i_ = 0; i_ < 4; ++i_) \
        _Pragma("unroll") for (int j_ = 0; j_ < 4; ++j_) \
            acc[i_ + 4 * (IH)][j_] = __builtin_amdgcn_mfma_f32_16x16x32_bf16( \
                af[i_], bf[j_], acc[i_ + 4 * (IH)][j_], 0, 0, 0); \
        __builtin_amdgcn_s_setprio(0); }

    // prologue: units 0..4  (tile0: Ak0,Bk0,Ak1,Bk1; tile1: Ak0)
    STG(0, 0, 0); STG(0, 0, 1); STG(0, 1, 0); STG(0, 1, 1); STG(1, 0, 0);

    int ph4 = (quad ^ ((r16 >> 1) & 3)) * 8;   // swizzled 8-bf16 slot
    int arow = (wm << 7) + r16;
    int brow = (wn << 6) + r16;
    bf16x8 af[4], bf[4];

    for (int t = 0; t + 1 < nt; ++t) {
        int c = t & 1;
        const short* Ab0 = &LA[c][0][arow * 32];
        const short* Bb0 = &LB[c][0][brow * 32];
        const short* Ab1 = &LA[c][1][arow * 32];
        const short* Bb1 = &LB[c][1][brow * 32];
        // phase 0: kk=0, i-half 0 ; stage (t+1) Bk0
        STG(t + 1, 0, 1);
        WAITV8; SBARF;
        PH_LOADB(Bb0); PH_LOADA(Ab0, 0); PH_MFMA(0);
        // phase 1: kk=0, i-half 1 ; stage (t+1) Ak1
        STG(t + 1, 1, 0);
        WAITV8; SBARF;
        PH_LOADA(Ab0, 1); PH_MFMA(1);
        // phase 2: kk=1, i-half 0 ; stage (t+1) Bk1
        STG(t + 1, 1, 1);
        WAITV8; SBARF;
        PH_LOADB(Bb1); PH_LOADA(Ab1, 0); PH_MFMA(0);
        // phase 3: kk=1, i-half 1 ; stage (t+2) Ak0
        if (t + 2 < nt) STG(t + 2, 0, 0);
        WAITV8; SBARF;
        PH_LOADA(Ab1, 1); PH_MFMA(1);
    }
    // tail tile nt-1: no staging; waits 4,-,0,-
    {
        int c = (nt - 1) & 1;
        const short* Ab0 = &LA[c][0][arow * 32];
        const short* Bb0 = &LB[c][0][brow * 32];
        const short* Ab1 = &LA[c][1][arow * 32];
        const short* Bb1 = &LB[c][1][brow * 32];
        WAITV4; SBARF;
        PH_LOADB(Bb0); PH_LOADA(Ab0, 0); PH_MFMA(0);
        PH_LOADA(Ab0, 1); PH_MFMA(1);
        WAITV0; SBARF;
        PH_LOADB(Bb1); PH_LOADA(Ab1, 0); PH_MFMA(0);
        PH_LOADA(Ab1, 1); PH_MFMA(1);
    }
#undef STG
#undef PH_LOADB
#undef PH_LOADA
#undef PH_MFMA

#pragma unroll
    for (int i = 0; i < 8; ++i) {
#pragma unroll
        for (int j = 0; j < 4; ++j) {
            int col = n0 + wn * 64 + j * 16 + r16;
            float bv = HAS_BIAS ? bias[col] : 0.f;
#pragma unroll
            for (int pr = 0; pr < 4; ++pr) {
                int row = m0 + wm * 128 + i * 16 + quad * 4 + pr;
                float v = acc[i][j][pr] + bv;
                if (HAS_ADD) v += addf[(size_t)row * N + col];
                if (OUT_F32) Cf[(size_t)row * N + col] = v;
                if (OUT_BF) Cbf[(size_t)row * N + col] = f2bf(v);
            }
        }
    }
}

// ---------------- Chunked linear scan (exact FFT-conv replacement) ----------------
__global__ __launch_bounds__(128) void scan_p1(const float* __restrict__ s3,
                                               const float* __restrict__ A_log,
                                               float* __restrict__ hbuf,
                                               float* __restrict__ Ebuf) {
    int s = threadIdx.x;
    int c = blockIdx.x, b = blockIdx.y;
    float a = expf(-expf(A_log[s]));
    float h = 0.f;
    size_t base = (size_t)b * SEQ_LEN + (size_t)c * LCHUNK;
#pragma unroll 8
    for (int i = 0; i < LCHUNK; ++i) {
        size_t r = base + i;
        float u = s3[r * 384 + s] * s3[r * 384 + 128 + s];
        h = a * h + u;
        hbuf[r * 128 + s] = h;
    }
    Ebuf[((size_t)b * NCHUNK + c) * 128 + s] = h;
}

__global__ __launch_bounds__(512) void scan_p2(const float* __restrict__ A_log,
                                               const float* __restrict__ Ebuf,
                                               float* __restrict__ Gbuf) {
    int tid = threadIdx.x;
    int b = tid >> 7, s = tid & 127;
    float pw = expf(-expf(A_log[s]) * (float)LCHUNK);
    float G = 0.f;
    for (int c0 = 0; c0 < NCHUNK; c0 += 16) {
        float e[16];
#pragma unroll
        for (int t = 0; t < 16; ++t)
            e[t] = Ebuf[((size_t)b * NCHUNK + c0 + t) * 128 + s];
#pragma unroll
        for (int t = 0; t < 16; ++t) {
            G = pw * G + e[t];
            Gbuf[((size_t)b * NCHUNK + c0 + t) * 128 + s] = G;
        }
    }
}

__global__ __launch_bounds__(128) void scan_p3(const float* __restrict__ s3,
                                               const float* __restrict__ A_log,
                                               const float* __restrict__ hbuf,
                                               const float* __restrict__ Gbuf,
                                               short* __restrict__ ys_bf) {
    int s = threadIdx.x;
    int c = blockIdx.x, b = blockIdx.y;
    float a = expf(-expf(A_log[s]));
    float carry = (c == 0) ? 0.f : Gbuf[((size_t)b * NCHUNK + c - 1) * 128 + s];
    float p = a;
    size_t base = (size_t)b * SEQ_LEN + (size_t)c * LCHUNK;
#pragma unroll 8
    for (int i = 0; i < LCHUNK; ++i) {
        size_t r = base + i;
        float h = hbuf[r * 128 + s] + p * carry;
        p *= a;
        ys_bf[r * 128 + s] = f2bf(h * s3[r * 384 + 256 + s]);
    }
}

extern "C" void kernel_launch(void* const* d_in, const int* in_sizes, int n_in,
                              void* d_out, int out_size, void* d_ws, size_t ws_size,
                              hipStream_t stream) {
    const float* x     = (const float*)d_in[0];
    const float* ln_g  = (const float*)d_in[1];
    const float* ln_b  = (const float*)d_in[2];
    const float* W_in  = (const float*)d_in[3];
    const float* b_in  = (const float*)d_in[4];
    const float* W_xs  = (const float*)d_in[5];
    const float* W_B   = (const float*)d_in[6];
    const float* b_B   = (const float*)d_in[7];
    const float* W_C   = (const float*)d_in[8];
    const float* b_C   = (const float*)d_in[9];
    const float* A_log = (const float*)d_in[10];
    const float* Dvec  = (const float*)d_in[11];
    const float* W_so  = (const float*)d_in[12];
    const float* W_out = (const float*)d_in[13];
    const float* b_out = (const float*)d_in[14];
    float* out = (float*)d_out;

    // ---- workspace carve (bytes) ----
    char* w = (char*)d_ws;
    size_t off = 0;
    short* xn_bf = (short*)(w + off);                       // region 0: 32 MiB
    float* hbuf  = (float*)(w + off);                       //   reuses region 0 after GEMM1
    short* ys_bf = (short*)(w + off + 8388608);             //   after hbuf (8 MiB)
    off += (size_t)NTOK * D_MODEL * 2;
    short* z_bf  = (short*)(w + off);                       // region 1: 32 MiB
    off += (size_t)NTOK * D_MODEL * 2;
    short* y1_bf = (short*)(w + off);                       // region 2: 32 MiB
    off += (size_t)NTOK * D_MODEL * 2;
    float* s3    = (float*)(w + off); off += (size_t)NTOK * 384 * 4;       // 24 MiB
    float* Ebuf  = (float*)(w + off); off += (size_t)BATCH * NCHUNK * 128 * 4;
    float* Gbuf  = (float*)(w + off); off += (size_t)BATCH * NCHUNK * 128 * 4;
    short* W_inT  = (short*)(w + off); off += (size_t)D_MODEL * D_MODEL * 2;
    short* W3T    = (short*)(w + off); off += (size_t)384 * D_MODEL * 2;
    short* W_soT  = (short*)(w + off); off += (size_t)D_MODEL * D_STATE * 2;
    short* W_outT = (short*)(w + off); off += (size_t)D_MODEL * D_MODEL * 2;
    float* bias3  = (float*)(w + off); off += 2048;

    // ---- weight prep (single launch) ----
    prep_kernel<<<2561, dim3(32, 8), 0, stream>>>(W_in, W_xs, W_B, W_C, W_so, W_out,
                                                  b_B, b_C, W_inT, W3T, W_soT, W_outT, bias3);

    // ---- 1) LayerNorm -> bf16 ----
    ln_kernel<<<NTOK, 256, 0, stream>>>(x, ln_g, ln_b, xn_bf);

    const int Mt = NTOK / 128;    // 128 (for 128^2 kernel)
    const int Mt2 = NTOK / 256;   // 64  (for 256^2 kernel)

    // ---- 2) z = xn @ W_in + b_in  (bf16 out) : 256^2 pipelined ----
    gemm256<1, 0, 0, 1, 1><<<Mt2 * 4, 512, 0, stream>>>(
        xn_bf, W_inT, b_in, nullptr, nullptr, z_bf, Mt2, 4, D_MODEL);

    // ---- 3) s3 = z @ [W_xs|W_B|W_C] + bias3  (f32) ----
    gemm_bf16<1, 0, 0, 0, 1, 0, 0><<<Mt * 3, 256, 0, stream>>>(
        z_bf, W3T, bias3, nullptr, nullptr, nullptr,
        s3, nullptr, Mt, 3, D_MODEL);

    // ---- 4) chunked scan (fp32 exact), fused *C_sel -> ys_bf ----
    scan_p1<<<dim3(NCHUNK, BATCH), 128, 0, stream>>>(s3, A_log, hbuf, Ebuf);
    scan_p2<<<1, 512, 0, stream>>>(A_log, Ebuf, Gbuf);
    scan_p3<<<dim3(NCHUNK, BATCH), 128, 0, stream>>>(s3, A_log, hbuf, Gbuf, ys_bf);

    // ---- 5) y1 = ys @ W_so + D*z  (bf16 out, bf16 addmat) ----
    gemm_bf16<0, 1, 1, 1, 0, 1, 1><<<Mt * 8, 256, 0, stream>>>(
        ys_bf, W_soT, nullptr, nullptr, z_bf, Dvec,
        nullptr, y1_bf, Mt, 8, D_STATE);

    // ---- 6) out = y1 @ W_out + b_out + x (f32 residual) : 256^2 pipelined ----
    gemm256<1, 1, 1, 0, 1><<<Mt2 * 4, 512, 0, stream>>>(
        y1_bf, W_outT, b_out, x, out, nullptr, Mt2, 4, D_MODEL);
}

// Round 2
// 293.915 us; speedup vs baseline: 1.0118x; 1.0118x over previous
//
#include <hip/hip_runtime.h>
#include <math.h>

#define D_MODEL 1024
#define D_STATE 128
#define SEQ_LEN 4096
#define BATCH 4
#define NTOK (BATCH * SEQ_LEN)      // 16384
#define LN_EPS 1e-3f
#define NCHUNK 128
#define LCHUNK (SEQ_LEN / NCHUNK)   // 32

typedef __attribute__((ext_vector_type(8))) short bf16x8;
typedef __attribute__((ext_vector_type(4))) float f32x4;

__device__ __forceinline__ short f2bf(float f) {
    union { float f; unsigned u; } v; v.f = f;
    unsigned r = v.u + 0x7FFFu + ((v.u >> 16) & 1u);   // RNE
    return (short)(r >> 16);
}
__device__ __forceinline__ float bf2f(short s) {
    union { unsigned u; float f; } v; v.u = ((unsigned)(unsigned short)s) << 16;
    return v.f;
}

// ---------------- LayerNorm -> bf16 output ----------------
__global__ __launch_bounds__(256) void ln_kernel(const float* __restrict__ x,
                                                 const float* __restrict__ gamma,
                                                 const float* __restrict__ beta,
                                                 short* __restrict__ xn_bf) {
    int row = blockIdx.x;
    const float4* xr = (const float4*)(x + (size_t)row * D_MODEL);
    float4 v = xr[threadIdx.x];
    float s1 = v.x + v.y + v.z + v.w;
    float s2 = v.x * v.x + v.y * v.y + v.z * v.z + v.w * v.w;
    for (int off = 32; off; off >>= 1) {
        s1 += __shfl_down(s1, off);
        s2 += __shfl_down(s2, off);
    }
    __shared__ float ls1[4], ls2[4];
    int wid = threadIdx.x >> 6, lane = threadIdx.x & 63;
    if (lane == 0) { ls1[wid] = s1; ls2[wid] = s2; }
    __syncthreads();
    s1 = ls1[0] + ls1[1] + ls1[2] + ls1[3];
    s2 = ls2[0] + ls2[1] + ls2[2] + ls2[3];
    float mu = s1 * (1.0f / D_MODEL);
    float var = s2 * (1.0f / D_MODEL) - mu * mu;
    float r = rsqrtf(var + LN_EPS);
    float4 g = ((const float4*)gamma)[threadIdx.x];
    float4 b = ((const float4*)beta)[threadIdx.x];
    short4 o;
    o.x = f2bf((v.x - mu) * r * g.x + b.x);
    o.y = f2bf((v.y - mu) * r * g.y + b.y);
    o.z = f2bf((v.z - mu) * r * g.z + b.z);
    o.w = f2bf((v.w - mu) * r * g.w + b.w);
    ((short4*)(xn_bf + (size_t)row * D_MODEL))[threadIdx.x] = o;
}

// ---------------- fused weight prep: all transposes + bias3 in ONE launch ----
__global__ __launch_bounds__(256) void prep_kernel(
    const float* __restrict__ W_in, const float* __restrict__ W_xs,
    const float* __restrict__ W_B, const float* __restrict__ W_C,
    const float* __restrict__ W_so, const float* __restrict__ W_out,
    const float* __restrict__ bB, const float* __restrict__ bC,
    short* __restrict__ W_inT, short* __restrict__ W3T,
    short* __restrict__ W_soT, short* __restrict__ W_outT,
    float* __restrict__ bias3) {
    int blk = blockIdx.x;
    const float* in; short* out; int K, N, tile;
    if (blk < 1024)      { in = W_in;  out = W_inT;           K = 1024; N = 1024; tile = blk; }
    else if (blk < 1152) { in = W_xs;  out = W3T;             K = 1024; N = 128;  tile = blk - 1024; }
    else if (blk < 1280) { in = W_B;   out = W3T + 128*1024;  K = 1024; N = 128;  tile = blk - 1152; }
    else if (blk < 1408) { in = W_C;   out = W3T + 256*1024;  K = 1024; N = 128;  tile = blk - 1280; }
    else if (blk < 1536) { in = W_so;  out = W_soT;           K = 128;  N = 1024; tile = blk - 1408; }
    else if (blk < 2560) { in = W_out; out = W_outT;          K = 1024; N = 1024; tile = blk - 1536; }
    else {
        int t = threadIdx.y * 32 + threadIdx.x;
        for (int n = t; n < 384; n += 256)
            bias3[n] = (n < 128) ? 0.f : ((n < 256) ? bB[n - 128] : bC[n - 256]);
        return;
    }
    __shared__ float t32[32][33];
    int ntiles = N / 32;
    int nb = (tile % ntiles) * 32, kb = (tile / ntiles) * 32;
    int tx = threadIdx.x, ty = threadIdx.y;   // 32 x 8
#pragma unroll
    for (int i = 0; i < 4; ++i)
        t32[ty + 8 * i][tx] = in[(size_t)(kb + ty + 8 * i) * N + nb + tx];
    __syncthreads();
#pragma unroll
    for (int i = 0; i < 4; ++i)
        out[(size_t)(nb + ty + 8 * i) * K + kb + tx] = f2bf(t32[tx][ty + 8 * i]);
}

// ---------------- bf16 MFMA GEMM: BK=64, XOR-swizzled LDS, XCD swizzle ------
// (retained for the N=384 projection GEMM and the K=128 W_so GEMM)
template<int HAS_BIAS, int HAS_ADD, int ADD_BF, int HAS_SCALE, int OUT_F32, int OUT_BF, int SWZ>
__global__ __launch_bounds__(256, 4) void gemm_bf16(
    const short* __restrict__ A, const short* __restrict__ BT,
    const float* __restrict__ bias,
    const float* __restrict__ addf, const short* __restrict__ addb,
    const float* __restrict__ addscale,
    float* __restrict__ Cf, short* __restrict__ Cbf,
    int Mt, int Nt, int K) {
    __shared__ short As[128 * 64];   // 16 KiB
    __shared__ short Bs[128 * 64];   // 16 KiB
    int p = blockIdx.x;
    int mtile, ntile;
    if (SWZ) {
        int k = p & 7, q = p >> 3;
        ntile = q & 7;
        mtile = k + 8 * (q >> 3);
    } else {
        mtile = p % Mt;
        ntile = p / Mt;
    }
    int m0 = mtile * 128, n0 = ntile * 128;
    int N = Nt * 128;
    int tid = threadIdx.x;
    int lane = tid & 63;
    int w = tid >> 6;
    int quad = lane >> 4, r16 = lane & 15;
    int wm = (w & 1) * 64, wn = (w >> 1) * 64;

    f32x4 acc[4][4] = {};

    for (int k0 = 0; k0 < K; k0 += 64) {
#pragma unroll
        for (int it = 0; it < 4; ++it) {
            int seg = it * 256 + tid;          // 0..1023
            int row = seg >> 3, slot = seg & 7;
            int kc8 = slot ^ (row & 7);
            const short* gp = A + (size_t)(m0 + row) * K + k0 + kc8 * 8;
            __builtin_amdgcn_global_load_lds(
                (const __attribute__((address_space(1))) unsigned*)gp,
                (__attribute__((address_space(3))) unsigned*)(As + seg * 8), 16, 0, 0);
        }
#pragma unroll
        for (int it = 0; it < 4; ++it) {
            int seg = it * 256 + tid;
            int row = seg >> 3, slot = seg & 7;
            int kc8 = slot ^ (row & 7);
            const short* gp = BT + (size_t)(n0 + row) * K + k0 + kc8 * 8;
            __builtin_amdgcn_global_load_lds(
                (const __attribute__((address_space(1))) unsigned*)gp,
                (__attribute__((address_space(3))) unsigned*)(Bs + seg * 8), 16, 0, 0);
        }
        __syncthreads();

        const short* abase = As + (wm + r16) * 64;
        const short* bbase = Bs + (wn + r16) * 64;
        int sw = r16 & 7;
#pragma unroll
        for (int kk = 0; kk < 2; ++kk) {
            int phys = ((quad + 4 * kk) ^ sw) * 8;
            bf16x8 af[4], bfr[4];
#pragma unroll
            for (int i = 0; i < 4; ++i) af[i] = *(const bf16x8*)(abase + i * 16 * 64 + phys);
#pragma unroll
            for (int j = 0; j < 4; ++j) bfr[j] = *(const bf16x8*)(bbase + j * 16 * 64 + phys);
#pragma unroll
            for (int i = 0; i < 4; ++i)
#pragma unroll
                for (int j = 0; j < 4; ++j)
                    acc[i][j] = __builtin_amdgcn_mfma_f32_16x16x32_bf16(af[i], bfr[j], acc[i][j], 0, 0, 0);
        }
        __syncthreads();
    }

#pragma unroll
    for (int i = 0; i < 4; ++i) {
#pragma unroll
        for (int j = 0; j < 4; ++j) {
            int col = n0 + wn + j * 16 + r16;
            float bv = HAS_BIAS ? bias[col] : 0.f;
            float sc = HAS_SCALE ? addscale[col] : 1.f;
#pragma unroll
            for (int pr = 0; pr < 4; ++pr) {
                int row = m0 + wm + i * 16 + quad * 4 + pr;
                float v = acc[i][j][pr] + bv;
                if (HAS_ADD) {
                    float av = ADD_BF ? bf2f(addb[(size_t)row * N + col])
                                      : addf[(size_t)row * N + col];
                    v += sc * av;
                }
                if (OUT_F32) Cf[(size_t)row * N + col] = v;
                if (OUT_BF) Cbf[(size_t)row * N + col] = f2bf(v);
            }
        }
    }
}

// ---------------- 256x256 8-phase template GEMM (m201-faithful port) --------
// Phase = {ds_read frags; STG 1 unit; [vmcnt @ phases 1,3]; BAR; setprio(1);
// 16 MFMA; setprio(0); BAR}. ds_reads issued BEFORE the barrier so their
// latency hides under barrier arrival; trailing barrier makes stage-issue
// into previously-read regions safe. vmcnt never drained in main loop.
// Stage unit = one (tile, kk-half, matrix) block: 256 rows x 32 cols = 16 KiB
// = 2 loads/thread. Steady-state: 4 units (8 loads) in flight -> vmcnt(8).
#define WAITV8 asm volatile("s_waitcnt vmcnt(8)" ::: "memory")
#define WAITV4 asm volatile("s_waitcnt vmcnt(4)" ::: "memory")
#define WAITV0 asm volatile("s_waitcnt vmcnt(0)" ::: "memory")
#define SBARF  do { __builtin_amdgcn_s_barrier(); asm volatile("" ::: "memory"); } while (0)

template<int HAS_BIAS, int HAS_ADD, int OUT_F32, int OUT_BF, int SWZ>
__global__ __launch_bounds__(512, 2) void gemm256(
    const short* __restrict__ A, const short* __restrict__ BT,
    const float* __restrict__ bias, const float* __restrict__ addf,
    float* __restrict__ Cf, short* __restrict__ Cbf,
    int Mt, int Nt, int K) {
    __shared__ short LA[2][2][8192];   // [dbuf][kk-half][256 rows x 32 cols]
    __shared__ short LB[2][2][8192];
    int p = blockIdx.x;
    int mtile, ntile;
    if (SWZ) {                 // bijective: grid = Mt*Nt, Mt multiple of 8
        int xcd = p & 7, q = p >> 3;
        ntile = q % Nt;
        mtile = xcd + 8 * (q / Nt);
    } else {
        mtile = p % Mt;
        ntile = p / Mt;
    }
    int m0 = mtile * 256, n0 = ntile * 256;
    int N = Nt * 256;
    int tid = threadIdx.x;
    int lane = tid & 63, w = tid >> 6;
    int quad = lane >> 4, r16 = lane & 15;
    int wm = w & 1, wn = w >> 1;       // 2 M-halves x 4 N-quarters
    int nt = K >> 6;                   // K-tiles of 64 (assumed >= 4)

    f32x4 acc[8][4] = {};

    // stage one unit: tile TU, K-chunk KK (0/1), matrix ISB (0=A,1=B).
    // LDS dest linear in tid; global source carries the inverse swizzle.
#define STG(TU, KK, ISB) do { \
        const short* g_ = (ISB) ? BT : A; \
        int rb_ = (ISB) ? n0 : m0; \
        short* l_ = (ISB) ? &LB[(TU) & 1][KK][0] : &LA[(TU) & 1][KK][0]; \
        _Pragma("unroll") \
        for (int r_ = 0; r_ < 2; ++r_) { \
            int seg_ = r_ * 512 + tid; \
            int row_ = seg_ >> 2, sl_ = seg_ & 3; \
            int kc_ = sl_ ^ ((row_ >> 1) & 3); \
            const short* gp_ = g_ + (size_t)(rb_ + row_) * K + (TU) * 64 + (KK) * 32 + kc_ * 8; \
            __builtin_amdgcn_global_load_lds( \
                (const __attribute__((address_space(1))) unsigned*)gp_, \
                (__attribute__((address_space(3))) unsigned*)(&l_[seg_ * 8]), 16, 0, 0); \
        } \
    } while (0)

#define RD_B(c, KK) { const short* Bb_ = &LB[c][KK][brow * 32]; \
        _Pragma("unroll") for (int j_ = 0; j_ < 4; ++j_) \
            bf[j_] = *(const bf16x8*)(Bb_ + j_ * 512 + ph4); }
#define RD_A(c, KK, IH) { const short* Ab_ = &LA[c][KK][arow * 32]; \
        _Pragma("unroll") for (int i_ = 0; i_ < 4; ++i_) \
            af[i_] = *(const bf16x8*)(Ab_ + (i_ + 4 * (IH)) * 512 + ph4); }
#define MM(IH) { __builtin_amdgcn_s_setprio(1); \
        _Pragma("unroll") for (int i_ = 0; i_ < 4; ++i_) \
        _Pragma("unroll") for (int j_ = 0; j_ < 4; ++j_) \
            acc[i_ + 4 * (IH)][j_] = __builtin_amdgcn_mfma_f32_16x16x32_bf16( \
                af[i_], bf[j_], acc[i_ + 4 * (IH)][j_], 0, 0, 0); \
        __builtin_amdgcn_s_setprio(0); }

    int ph4 = (quad ^ ((r16 >> 1) & 3)) * 8;   // swizzled 8-bf16 slot
    int arow = (wm << 7) + r16;
    int brow = (wn << 6) + r16;
    bf16x8 af[4], bf[4];

    // prologue: tile0 {Ak0,Bk0,Ak1,Bk1}, tile1 {Ak0,Bk0}; then wait+barrier
    STG(0, 0, 0); STG(0, 0, 1); STG(0, 1, 0); STG(0, 1, 1);
    STG(1, 0, 0); STG(1, 0, 1);
    WAITV8; SBARF;

    for (int t = 0; t + 2 < nt; ++t) {
        int c = t & 1;
        // phase 0: kk0, i-half0 ; stage A-kk1(t+1)
        RD_B(c, 0); RD_A(c, 0, 0); STG(t + 1, 1, 0);
        SBARF; MM(0); SBARF;
        // phase 1: kk0, i-half1 ; stage B-kk1(t+1) ; vmcnt(8)
        RD_A(c, 0, 1); STG(t + 1, 1, 1); WAITV8;
        SBARF; MM(1); SBARF;
        // phase 2: kk1, i-half0 ; stage A-kk0(t+2)
        RD_B(c, 1); RD_A(c, 1, 0); STG(t + 2, 0, 0);
        SBARF; MM(0); SBARF;
        // phase 3: kk1, i-half1 ; stage B-kk0(t+2) ; vmcnt(8)
        RD_A(c, 1, 1); STG(t + 2, 0, 1); WAITV8;
        SBARF; MM(1); SBARF;
    }
    {   // tile nt-2: stage only kk1(nt-1); drain 8 -> 4
        int c = (nt - 2) & 1;
        RD_B(c, 0); RD_A(c, 0, 0); STG(nt - 1, 1, 0);
        SBARF; MM(0); SBARF;
        RD_A(c, 0, 1); STG(nt - 1, 1, 1); WAITV8;
        SBARF; MM(1); SBARF;
        RD_B(c, 1); RD_A(c, 1, 0);
        SBARF; MM(0); SBARF;
        RD_A(c, 1, 1); WAITV4;
        SBARF; MM(1); SBARF;
    }
    {   // tile nt-1: no staging; drain 0 before kk1 reads
        int c = (nt - 1) & 1;
        RD_B(c, 0); RD_A(c, 0, 0);
        SBARF; MM(0); SBARF;
        RD_A(c, 0, 1); WAITV0;
        SBARF; MM(1); SBARF;
        RD_B(c, 1); RD_A(c, 1, 0);
        SBARF; MM(0); SBARF;
        RD_A(c, 1, 1);
        SBARF; MM(1);
    }
#undef STG
#undef RD_B
#undef RD_A
#undef MM

#pragma unroll
    for (int i = 0; i < 8; ++i) {
#pragma unroll
        for (int j = 0; j < 4; ++j) {
            int col = n0 + wn * 64 + j * 16 + r16;
            float bv = HAS_BIAS ? bias[col] : 0.f;
#pragma unroll
            for (int pr = 0; pr < 4; ++pr) {
                int row = m0 + wm * 128 + i * 16 + quad * 4 + pr;
                float v = acc[i][j][pr] + bv;
                if (HAS_ADD) v += addf[(size_t)row * N + col];
                if (OUT_F32) Cf[(size_t)row * N + col] = v;
                if (OUT_BF) Cbf[(size_t)row * N + col] = f2bf(v);
            }
        }
    }
}

// ---------------- Chunked linear scan (exact FFT-conv replacement) ----------------
__global__ __launch_bounds__(128) void scan_p1(const float* __restrict__ s3,
                                               const float* __restrict__ A_log,
                                               float* __restrict__ hbuf,
                                               float* __restrict__ Ebuf) {
    int s = threadIdx.x;
    int c = blockIdx.x, b = blockIdx.y;
    float a = expf(-expf(A_log[s]));
    float h = 0.f;
    size_t base = (size_t)b * SEQ_LEN + (size_t)c * LCHUNK;
#pragma unroll 8
    for (int i = 0; i < LCHUNK; ++i) {
        size_t r = base + i;
        float u = s3[r * 384 + s] * s3[r * 384 + 128 + s];
        h = a * h + u;
        hbuf[r * 128 + s] = h;
    }
    Ebuf[((size_t)b * NCHUNK + c) * 128 + s] = h;
}

__global__ __launch_bounds__(512) void scan_p2(const float* __restrict__ A_log,
                                               const float* __restrict__ Ebuf,
                                               float* __restrict__ Gbuf) {
    int tid = threadIdx.x;
    int b = tid >> 7, s = tid & 127;
    float pw = expf(-expf(A_log[s]) * (float)LCHUNK);
    float G = 0.f;
    for (int c0 = 0; c0 < NCHUNK; c0 += 16) {
        float e[16];
#pragma unroll
        for (int t = 0; t < 16; ++t)
            e[t] = Ebuf[((size_t)b * NCHUNK + c0 + t) * 128 + s];
#pragma unroll
        for (int t = 0; t < 16; ++t) {
            G = pw * G + e[t];
            Gbuf[((size_t)b * NCHUNK + c0 + t) * 128 + s] = G;
        }
    }
}

__global__ __launch_bounds__(128) void scan_p3(const float* __restrict__ s3,
                                               const float* __restrict__ A_log,
                                               const float* __restrict__ hbuf,
                                               const float* __restrict__ Gbuf,
                                               short* __restrict__ ys_bf) {
    int s = threadIdx.x;
    int c = blockIdx.x, b = blockIdx.y;
    float a = expf(-expf(A_log[s]));
    float carry = (c == 0) ? 0.f : Gbuf[((size_t)b * NCHUNK + c - 1) * 128 + s];
    float p = a;
    size_t base = (size_t)b * SEQ_LEN + (size_t)c * LCHUNK;
#pragma unroll 8
    for (int i = 0; i < LCHUNK; ++i) {
        size_t r = base + i;
        float h = hbuf[r * 128 + s] + p * carry;
        p *= a;
        ys_bf[r * 128 + s] = f2bf(h * s3[r * 384 + 256 + s]);
    }
}

extern "C" void kernel_launch(void* const* d_in, const int* in_sizes, int n_in,
                              void* d_out, int out_size, void* d_ws, size_t ws_size,
                              hipStream_t stream) {
    const float* x     = (const float*)d_in[0];
    const float* ln_g  = (const float*)d_in[1];
    const float* ln_b  = (const float*)d_in[2];
    const float* W_in  = (const float*)d_in[3];
    const float* b_in  = (const float*)d_in[4];
    const float* W_xs  = (const float*)d_in[5];
    const float* W_B   = (const float*)d_in[6];
    const float* b_B   = (const float*)d_in[7];
    const float* W_C   = (const float*)d_in[8];
    const float* b_C   = (const float*)d_in[9];
    const float* A_log = (const float*)d_in[10];
    const float* Dvec  = (const float*)d_in[11];
    const float* W_so  = (const float*)d_in[12];
    const float* W_out = (const float*)d_in[13];
    const float* b_out = (const float*)d_in[14];
    float* out = (float*)d_out;

    // ---- workspace carve (bytes) ----
    char* w = (char*)d_ws;
    size_t off = 0;
    short* xn_bf = (short*)(w + off);                       // region 0: 32 MiB
    float* hbuf  = (float*)(w + off);                       //   reuses region 0 after GEMM1
    short* ys_bf = (short*)(w + off + 8388608);             //   after hbuf (8 MiB)
    off += (size_t)NTOK * D_MODEL * 2;
    short* z_bf  = (short*)(w + off);                       // region 1: 32 MiB
    off += (size_t)NTOK * D_MODEL * 2;
    short* y1_bf = (short*)(w + off);                       // region 2: 32 MiB
    off += (size_t)NTOK * D_MODEL * 2;
    float* s3    = (float*)(w + off); off += (size_t)NTOK * 384 * 4;       // 24 MiB
    float* Ebuf  = (float*)(w + off); off += (size_t)BATCH * NCHUNK * 128 * 4;
    float* Gbuf  = (float*)(w + off); off += (size_t)BATCH * NCHUNK * 128 * 4;
    short* W_inT  = (short*)(w + off); off += (size_t)D_MODEL * D_MODEL * 2;
    short* W3T    = (short*)(w + off); off += (size_t)384 * D_MODEL * 2;
    short* W_soT  = (short*)(w + off); off += (size_t)D_MODEL * D_STATE * 2;
    short* W_outT = (short*)(w + off); off += (size_t)D_MODEL * D_MODEL * 2;
    float* bias3  = (float*)(w + off); off += 2048;

    // ---- weight prep (single launch) ----
    prep_kernel<<<2561, dim3(32, 8), 0, stream>>>(W_in, W_xs, W_B, W_C, W_so, W_out,
                                                  b_B, b_C, W_inT, W3T, W_soT, W_outT, bias3);

    // ---- 1) LayerNorm -> bf16 ----
    ln_kernel<<<NTOK, 256, 0, stream>>>(x, ln_g, ln_b, xn_bf);

    const int Mt = NTOK / 128;    // 128 (for 128^2 kernel)
    const int Mt2 = NTOK / 256;   // 64  (for 256^2 kernel)

    // ---- 2) z = xn @ W_in + b_in  (bf16 out) : 256^2 pipelined ----
    gemm256<1, 0, 0, 1, 1><<<Mt2 * 4, 512, 0, stream>>>(
        xn_bf, W_inT, b_in, nullptr, nullptr, z_bf, Mt2, 4, D_MODEL);

    // ---- 3) s3 = z @ [W_xs|W_B|W_C] + bias3  (f32) ----
    gemm_bf16<1, 0, 0, 0, 1, 0, 0><<<Mt * 3, 256, 0, stream>>>(
        z_bf, W3T, bias3, nullptr, nullptr, nullptr,
        s3, nullptr, Mt, 3, D_MODEL);

    // ---- 4) chunked scan (fp32 exact), fused *C_sel -> ys_bf ----
    scan_p1<<<dim3(NCHUNK, BATCH), 128, 0, stream>>>(s3, A_log, hbuf, Ebuf);
    scan_p2<<<1, 512, 0, stream>>>(A_log, Ebuf, Gbuf);
    scan_p3<<<dim3(NCHUNK, BATCH), 128, 0, stream>>>(s3, A_log, hbuf, Gbuf, ys_bf);

    // ---- 5) y1 = ys @ W_so + D*z  (bf16 out, bf16 addmat) ----
    gemm_bf16<0, 1, 1, 1, 0, 1, 1><<<Mt * 8, 256, 0, stream>>>(
        ys_bf, W_soT, nullptr, nullptr, z_bf, Dvec,
        nullptr, y1_bf, Mt, 8, D_STATE);

    // ---- 6) out = y1 @ W_out + b_out + x (f32 residual) : 256^2 pipelined ----
    gemm256<1, 1, 1, 0, 1><<<Mt2 * 4, 512, 0, stream>>>(
        y1_bf, W_outT, b_out, x, out, nullptr, Mt2, 4, D_MODEL);
}

// Round 3
// 292.407 us; speedup vs baseline: 1.0170x; 1.0052x over previous
//
#include <hip/hip_runtime.h>
#include <math.h>

#define D_MODEL 1024
#define D_STATE 128
#define SEQ_LEN 4096
#define BATCH 4
#define NTOK (BATCH * SEQ_LEN)      // 16384
#define LN_EPS 1e-3f
#define NCHUNK 128
#define LCHUNK (SEQ_LEN / NCHUNK)   // 32

typedef __attribute__((ext_vector_type(8))) short bf16x8;
typedef __attribute__((ext_vector_type(4))) float f32x4;

__device__ __forceinline__ short f2bf(float f) {
    union { float f; unsigned u; } v; v.f = f;
    unsigned r = v.u + 0x7FFFu + ((v.u >> 16) & 1u);   // RNE
    return (short)(r >> 16);
}
__device__ __forceinline__ float bf2f(short s) {
    union { unsigned u; float f; } v; v.u = ((unsigned)(unsigned short)s) << 16;
    return v.f;
}

// Packed-B layout: BT[n][k] lives at
// [nt=n>>7][t0=k>>6][kk=(k>>5)&1][j'=(n&127)>>4][quad=(k>>3)&3][r16=n&15][e=k&7]
// so a wave's MFMA B-fragment load is addr = base + lane*16B (fully coalesced,
// no LDS, no swizzle). Strides (shorts): e:1, r16:8, quad:128, j':512,
// kk:4096, t0:8192, nt:(K>>6)*8192.
__device__ __forceinline__ size_t bpack_off(int n, int k, int K) {
    return ((((size_t)(n >> 7) * (K >> 6) + (k >> 6)) * 2 + ((k >> 5) & 1)) * 8
            + ((n & 127) >> 4)) * 512 + (size_t)(((k >> 3) & 3) * 128 + (n & 15) * 8 + (k & 7));
}

// ---------------- LayerNorm -> bf16 output ----------------
__global__ __launch_bounds__(256) void ln_kernel(const float* __restrict__ x,
                                                 const float* __restrict__ gamma,
                                                 const float* __restrict__ beta,
                                                 short* __restrict__ xn_bf) {
    int row = blockIdx.x;
    const float4* xr = (const float4*)(x + (size_t)row * D_MODEL);
    float4 v = xr[threadIdx.x];
    float s1 = v.x + v.y + v.z + v.w;
    float s2 = v.x * v.x + v.y * v.y + v.z * v.z + v.w * v.w;
    for (int off = 32; off; off >>= 1) {
        s1 += __shfl_down(s1, off);
        s2 += __shfl_down(s2, off);
    }
    __shared__ float ls1[4], ls2[4];
    int wid = threadIdx.x >> 6, lane = threadIdx.x & 63;
    if (lane == 0) { ls1[wid] = s1; ls2[wid] = s2; }
    __syncthreads();
    s1 = ls1[0] + ls1[1] + ls1[2] + ls1[3];
    s2 = ls2[0] + ls2[1] + ls2[2] + ls2[3];
    float mu = s1 * (1.0f / D_MODEL);
    float var = s2 * (1.0f / D_MODEL) - mu * mu;
    float r = rsqrtf(var + LN_EPS);
    float4 g = ((const float4*)gamma)[threadIdx.x];
    float4 b = ((const float4*)beta)[threadIdx.x];
    short4 o;
    o.x = f2bf((v.x - mu) * r * g.x + b.x);
    o.y = f2bf((v.y - mu) * r * g.y + b.y);
    o.z = f2bf((v.z - mu) * r * g.z + b.z);
    o.w = f2bf((v.w - mu) * r * g.w + b.w);
    ((short4*)(xn_bf + (size_t)row * D_MODEL))[threadIdx.x] = o;
}

// ---------------- fused weight prep: transposes -> PACKED B + bias3 ----------
__global__ __launch_bounds__(256) void prep_kernel(
    const float* __restrict__ W_in, const float* __restrict__ W_xs,
    const float* __restrict__ W_B, const float* __restrict__ W_C,
    const float* __restrict__ W_so, const float* __restrict__ W_out,
    const float* __restrict__ bB, const float* __restrict__ bC,
    short* __restrict__ W_inT, short* __restrict__ W3T,
    short* __restrict__ W_soT, short* __restrict__ W_outT,
    float* __restrict__ bias3) {
    int blk = blockIdx.x;
    const float* in; short* out; int K, N, tile;
    if (blk < 1024)      { in = W_in;  out = W_inT;           K = 1024; N = 1024; tile = blk; }
    else if (blk < 1152) { in = W_xs;  out = W3T;             K = 1024; N = 128;  tile = blk - 1024; }
    else if (blk < 1280) { in = W_B;   out = W3T + 128*1024;  K = 1024; N = 128;  tile = blk - 1152; }
    else if (blk < 1408) { in = W_C;   out = W3T + 256*1024;  K = 1024; N = 128;  tile = blk - 1280; }
    else if (blk < 1536) { in = W_so;  out = W_soT;           K = 128;  N = 1024; tile = blk - 1408; }
    else if (blk < 2560) { in = W_out; out = W_outT;          K = 1024; N = 1024; tile = blk - 1536; }
    else {
        int t = threadIdx.y * 32 + threadIdx.x;
        for (int n = t; n < 384; n += 256)
            bias3[n] = (n < 128) ? 0.f : ((n < 256) ? bB[n - 128] : bC[n - 256]);
        return;
    }
    __shared__ float t32[32][33];
    int ntiles = N / 32;
    int nb = (tile % ntiles) * 32, kb = (tile / ntiles) * 32;
    int tx = threadIdx.x, ty = threadIdx.y;   // 32 x 8
#pragma unroll
    for (int i = 0; i < 4; ++i)
        t32[ty + 8 * i][tx] = in[(size_t)(kb + ty + 8 * i) * N + nb + tx];
    __syncthreads();
#pragma unroll
    for (int i = 0; i < 4; ++i) {
        int n = nb + ty + 8 * i;   // local n within this matrix region
        int k = kb + tx;
        out[bpack_off(n, k, K)] = f2bf(t32[tx][ty + 8 * i]);
    }
}

// ---------------- bf16 MFMA GEMM: A via LDS (swizzled), B direct-from-L2 ----
// B fragments load as coalesced global dwordx4 from the packed layout; only A
// is staged through LDS (16 KiB), halving LDS traffic and removing B from the
// pre-barrier vmcnt drain.
template<int HAS_BIAS, int HAS_ADD, int ADD_BF, int HAS_SCALE, int OUT_F32, int OUT_BF, int SWZ>
__global__ __launch_bounds__(256, 4) void gemm_bf16(
    const short* __restrict__ A, const short* __restrict__ BT,
    const float* __restrict__ bias,
    const float* __restrict__ addf, const short* __restrict__ addb,
    const float* __restrict__ addscale,
    float* __restrict__ Cf, short* __restrict__ Cbf,
    int Mt, int Nt, int K) {
    __shared__ short As[128 * 64];   // 16 KiB
    int p = blockIdx.x;
    int mtile, ntile;
    if (SWZ) {           // xcd = p&7; each XCD runs (m, n=0..7) consecutively
        int k = p & 7, q = p >> 3;
        ntile = q & 7;
        mtile = k + 8 * (q >> 3);
    } else {
        mtile = p % Mt;
        ntile = p / Mt;
    }
    int m0 = mtile * 128, n0 = ntile * 128;
    int N = Nt * 128;
    int tid = threadIdx.x;
    int lane = tid & 63;
    int w = tid >> 6;
    int quad = lane >> 4, r16 = lane & 15;
    int wm = (w & 1) * 64, wn = (w >> 1) * 64;
    int wn4 = (w >> 1) * 4;            // j' base for packed-B reads

    f32x4 acc[4][4] = {};

    int kt = K >> 6;
    for (int t = 0; t < kt; ++t) {
        int k0 = t << 6;
#pragma unroll
        for (int it = 0; it < 4; ++it) {
            int seg = it * 256 + tid;          // 0..1023
            int row = seg >> 3, slot = seg & 7;
            int kc8 = slot ^ (row & 7);
            const short* gp = A + (size_t)(m0 + row) * K + k0 + kc8 * 8;
            __builtin_amdgcn_global_load_lds(
                (const __attribute__((address_space(1))) unsigned*)gp,
                (__attribute__((address_space(3))) unsigned*)(As + seg * 8), 16, 0, 0);
        }
        __syncthreads();

        // packed-B base for this (ntile, t): shorts
        int bbase = (((ntile * kt + t) * 2) * 8 + wn4) * 512 + lane * 8;
        const short* abase = As + (wm + r16) * 64;
        int sw = r16 & 7;
#pragma unroll
        for (int kk = 0; kk < 2; ++kk) {
            bf16x8 bfr[4];
#pragma unroll
            for (int j = 0; j < 4; ++j)
                bfr[j] = *(const bf16x8*)(BT + bbase + kk * 4096 + j * 512);
            int phys = ((quad + 4 * kk) ^ sw) * 8;
            bf16x8 af[4];
#pragma unroll
            for (int i = 0; i < 4; ++i) af[i] = *(const bf16x8*)(abase + i * 16 * 64 + phys);
#pragma unroll
            for (int i = 0; i < 4; ++i)
#pragma unroll
                for (int j = 0; j < 4; ++j)
                    acc[i][j] = __builtin_amdgcn_mfma_f32_16x16x32_bf16(af[i], bfr[j], acc[i][j], 0, 0, 0);
        }
        __syncthreads();
    }

#pragma unroll
    for (int i = 0; i < 4; ++i) {
#pragma unroll
        for (int j = 0; j < 4; ++j) {
            int col = n0 + wn + j * 16 + r16;
            float bv = HAS_BIAS ? bias[col] : 0.f;
            float sc = HAS_SCALE ? addscale[col] : 1.f;
#pragma unroll
            for (int pr = 0; pr < 4; ++pr) {
                int row = m0 + wm + i * 16 + quad * 4 + pr;
                float v = acc[i][j][pr] + bv;
                if (HAS_ADD) {
                    float av = ADD_BF ? bf2f(addb[(size_t)row * N + col])
                                      : addf[(size_t)row * N + col];
                    v += sc * av;
                }
                if (OUT_F32) Cf[(size_t)row * N + col] = v;
                if (OUT_BF) Cbf[(size_t)row * N + col] = f2bf(v);
            }
        }
    }
}

// ---------------- Chunked linear scan (exact FFT-conv replacement) ----------------
__global__ __launch_bounds__(128) void scan_p1(const float* __restrict__ s3,
                                               const float* __restrict__ A_log,
                                               float* __restrict__ hbuf,
                                               float* __restrict__ Ebuf) {
    int s = threadIdx.x;
    int c = blockIdx.x, b = blockIdx.y;
    float a = expf(-expf(A_log[s]));
    float h = 0.f;
    size_t base = (size_t)b * SEQ_LEN + (size_t)c * LCHUNK;
#pragma unroll 8
    for (int i = 0; i < LCHUNK; ++i) {
        size_t r = base + i;
        float u = s3[r * 384 + s] * s3[r * 384 + 128 + s];
        h = a * h + u;
        hbuf[r * 128 + s] = h;
    }
    Ebuf[((size_t)b * NCHUNK + c) * 128 + s] = h;
}

__global__ __launch_bounds__(512) void scan_p2(const float* __restrict__ A_log,
                                               const float* __restrict__ Ebuf,
                                               float* __restrict__ Gbuf) {
    int tid = threadIdx.x;
    int b = tid >> 7, s = tid & 127;
    float pw = expf(-expf(A_log[s]) * (float)LCHUNK);
    float G = 0.f;
    for (int c0 = 0; c0 < NCHUNK; c0 += 16) {
        float e[16];
#pragma unroll
        for (int t = 0; t < 16; ++t)
            e[t] = Ebuf[((size_t)b * NCHUNK + c0 + t) * 128 + s];
#pragma unroll
        for (int t = 0; t < 16; ++t) {
            G = pw * G + e[t];
            Gbuf[((size_t)b * NCHUNK + c0 + t) * 128 + s] = G;
        }
    }
}

__global__ __launch_bounds__(128) void scan_p3(const float* __restrict__ s3,
                                               const float* __restrict__ A_log,
                                               const float* __restrict__ hbuf,
                                               const float* __restrict__ Gbuf,
                                               short* __restrict__ ys_bf) {
    int s = threadIdx.x;
    int c = blockIdx.x, b = blockIdx.y;
    float a = expf(-expf(A_log[s]));
    float carry = (c == 0) ? 0.f : Gbuf[((size_t)b * NCHUNK + c - 1) * 128 + s];
    float p = a;
    size_t base = (size_t)b * SEQ_LEN + (size_t)c * LCHUNK;
#pragma unroll 8
    for (int i = 0; i < LCHUNK; ++i) {
        size_t r = base + i;
        float h = hbuf[r * 128 + s] + p * carry;
        p *= a;
        ys_bf[r * 128 + s] = f2bf(h * s3[r * 384 + 256 + s]);
    }
}

extern "C" void kernel_launch(void* const* d_in, const int* in_sizes, int n_in,
                              void* d_out, int out_size, void* d_ws, size_t ws_size,
                              hipStream_t stream) {
    const float* x     = (const float*)d_in[0];
    const float* ln_g  = (const float*)d_in[1];
    const float* ln_b  = (const float*)d_in[2];
    const float* W_in  = (const float*)d_in[3];
    const float* b_in  = (const float*)d_in[4];
    const float* W_xs  = (const float*)d_in[5];
    const float* W_B   = (const float*)d_in[6];
    const float* b_B   = (const float*)d_in[7];
    const float* W_C   = (const float*)d_in[8];
    const float* b_C   = (const float*)d_in[9];
    const float* A_log = (const float*)d_in[10];
    const float* Dvec  = (const float*)d_in[11];
    const float* W_so  = (const float*)d_in[12];
    const float* W_out = (const float*)d_in[13];
    const float* b_out = (const float*)d_in[14];
    float* out = (float*)d_out;

    // ---- workspace carve (bytes) ----
    char* w = (char*)d_ws;
    size_t off = 0;
    short* xn_bf = (short*)(w + off);                       // region 0: 32 MiB
    float* hbuf  = (float*)(w + off);                       //   reuses region 0 after GEMM1
    short* ys_bf = (short*)(w + off + 8388608);             //   after hbuf (8 MiB)
    off += (size_t)NTOK * D_MODEL * 2;
    short* z_bf  = (short*)(w + off);                       // region 1: 32 MiB
    off += (size_t)NTOK * D_MODEL * 2;
    short* y1_bf = (short*)(w + off);                       // region 2: 32 MiB
    off += (size_t)NTOK * D_MODEL * 2;
    float* s3    = (float*)(w + off); off += (size_t)NTOK * 384 * 4;       // 24 MiB
    float* Ebuf  = (float*)(w + off); off += (size_t)BATCH * NCHUNK * 128 * 4;
    float* Gbuf  = (float*)(w + off); off += (size_t)BATCH * NCHUNK * 128 * 4;
    short* W_inT  = (short*)(w + off); off += (size_t)D_MODEL * D_MODEL * 2;
    short* W3T    = (short*)(w + off); off += (size_t)384 * D_MODEL * 2;
    short* W_soT  = (short*)(w + off); off += (size_t)D_MODEL * D_STATE * 2;
    short* W_outT = (short*)(w + off); off += (size_t)D_MODEL * D_MODEL * 2;
    float* bias3  = (float*)(w + off); off += 2048;

    // ---- weight prep (single launch; writes packed-B layouts) ----
    prep_kernel<<<2561, dim3(32, 8), 0, stream>>>(W_in, W_xs, W_B, W_C, W_so, W_out,
                                                  b_B, b_C, W_inT, W3T, W_soT, W_outT, bias3);

    // ---- 1) LayerNorm -> bf16 ----
    ln_kernel<<<NTOK, 256, 0, stream>>>(x, ln_g, ln_b, xn_bf);

    const int Mt = NTOK / 128;   // 128
    // ---- 2) z = xn @ W_in + b_in  (bf16) ----
    gemm_bf16<1, 0, 0, 0, 0, 1, 1><<<Mt * 8, 256, 0, stream>>>(
        xn_bf, W_inT, b_in, nullptr, nullptr, nullptr,
        nullptr, z_bf, Mt, 8, D_MODEL);

    // ---- 3) s3 = z @ [W_xs|W_B|W_C] + bias3  (f32) ----
    gemm_bf16<1, 0, 0, 0, 1, 0, 0><<<Mt * 3, 256, 0, stream>>>(
        z_bf, W3T, bias3, nullptr, nullptr, nullptr,
        s3, nullptr, Mt, 3, D_MODEL);

    // ---- 4) chunked scan (fp32 exact), fused *C_sel -> ys_bf ----
    scan_p1<<<dim3(NCHUNK, BATCH), 128, 0, stream>>>(s3, A_log, hbuf, Ebuf);
    scan_p2<<<1, 512, 0, stream>>>(A_log, Ebuf, Gbuf);
    scan_p3<<<dim3(NCHUNK, BATCH), 128, 0, stream>>>(s3, A_log, hbuf, Gbuf, ys_bf);

    // ---- 5) y1 = ys @ W_so + D*z  (bf16 out, bf16 addmat) ----
    gemm_bf16<0, 1, 1, 1, 0, 1, 1><<<Mt * 8, 256, 0, stream>>>(
        ys_bf, W_soT, nullptr, nullptr, z_bf, Dvec,
        nullptr, y1_bf, Mt, 8, D_STATE);

    // ---- 6) out = y1 @ W_out + b_out + x (f32 residual) ----
    gemm_bf16<1, 1, 0, 0, 1, 0, 1><<<Mt * 8, 256, 0, stream>>>(
        y1_bf, W_outT, b_out, x, nullptr, nullptr,
        out, nullptr, Mt, 8, D_MODEL);
}

// Round 5
// 279.233 us; speedup vs baseline: 1.0650x; 1.0472x over previous
//
#include <hip/hip_runtime.h>
#include <math.h>

#define D_MODEL 1024
#define D_STATE 128
#define SEQ_LEN 4096
#define BATCH 4
#define NTOK (BATCH * SEQ_LEN)      // 16384
#define LN_EPS 1e-3f
#define NCHUNK 128
#define LCHUNK (SEQ_LEN / NCHUNK)   // 32

typedef __attribute__((ext_vector_type(8))) short bf16x8;
typedef __attribute__((ext_vector_type(4))) float f32x4;

__device__ __forceinline__ short f2bf(float f) {
    union { float f; unsigned u; } v; v.f = f;
    unsigned r = v.u + 0x7FFFu + ((v.u >> 16) & 1u);   // RNE
    return (short)(r >> 16);
}
__device__ __forceinline__ float bf2f(short s) {
    union { unsigned u; float f; } v; v.u = ((unsigned)(unsigned short)s) << 16;
    return v.f;
}

// ---------------- LayerNorm -> bf16 output ----------------
__global__ __launch_bounds__(256) void ln_kernel(const float* __restrict__ x,
                                                 const float* __restrict__ gamma,
                                                 const float* __restrict__ beta,
                                                 short* __restrict__ xn_bf) {
    int row = blockIdx.x;
    const float4* xr = (const float4*)(x + (size_t)row * D_MODEL);
    float4 v = xr[threadIdx.x];
    float s1 = v.x + v.y + v.z + v.w;
    float s2 = v.x * v.x + v.y * v.y + v.z * v.z + v.w * v.w;
    for (int off = 32; off; off >>= 1) {
        s1 += __shfl_down(s1, off);
        s2 += __shfl_down(s2, off);
    }
    __shared__ float ls1[4], ls2[4];
    int wid = threadIdx.x >> 6, lane = threadIdx.x & 63;
    if (lane == 0) { ls1[wid] = s1; ls2[wid] = s2; }
    __syncthreads();
    s1 = ls1[0] + ls1[1] + ls1[2] + ls1[3];
    s2 = ls2[0] + ls2[1] + ls2[2] + ls2[3];
    float mu = s1 * (1.0f / D_MODEL);
    float var = s2 * (1.0f / D_MODEL) - mu * mu;
    float r = rsqrtf(var + LN_EPS);
    float4 g = ((const float4*)gamma)[threadIdx.x];
    float4 b = ((const float4*)beta)[threadIdx.x];
    short4 o;
    o.x = f2bf((v.x - mu) * r * g.x + b.x);
    o.y = f2bf((v.y - mu) * r * g.y + b.y);
    o.z = f2bf((v.z - mu) * r * g.z + b.z);
    o.w = f2bf((v.w - mu) * r * g.w + b.w);
    ((short4*)(xn_bf + (size_t)row * D_MODEL))[threadIdx.x] = o;
}

// ---------------- fused weight prep: all transposes + bias3 in ONE launch ----
__global__ __launch_bounds__(256) void prep_kernel(
    const float* __restrict__ W_in, const float* __restrict__ W_xs,
    const float* __restrict__ W_B, const float* __restrict__ W_C,
    const float* __restrict__ W_so, const float* __restrict__ W_out,
    const float* __restrict__ bB, const float* __restrict__ bC,
    short* __restrict__ W_inT, short* __restrict__ W3T,
    short* __restrict__ W_soT, short* __restrict__ W_outT,
    float* __restrict__ bias3) {
    int blk = blockIdx.x;
    const float* in; short* out; int K, N, tile;
    if (blk < 1024)      { in = W_in;  out = W_inT;           K = 1024; N = 1024; tile = blk; }
    else if (blk < 1152) { in = W_xs;  out = W3T;             K = 1024; N = 128;  tile = blk - 1024; }
    else if (blk < 1280) { in = W_B;   out = W3T + 128*1024;  K = 1024; N = 128;  tile = blk - 1152; }
    else if (blk < 1408) { in = W_C;   out = W3T + 256*1024;  K = 1024; N = 128;  tile = blk - 1280; }
    else if (blk < 1536) { in = W_so;  out = W_soT;           K = 128;  N = 1024; tile = blk - 1408; }
    else if (blk < 2560) { in = W_out; out = W_outT;          K = 1024; N = 1024; tile = blk - 1536; }
    else {
        int t = threadIdx.y * 32 + threadIdx.x;
        for (int n = t; n < 384; n += 256)
            bias3[n] = (n < 128) ? 0.f : ((n < 256) ? bB[n - 128] : bC[n - 256]);
        return;
    }
    __shared__ float t32[32][33];
    int ntiles = N / 32;
    int nb = (tile % ntiles) * 32, kb = (tile / ntiles) * 32;
    int tx = threadIdx.x, ty = threadIdx.y;   // 32 x 8
#pragma unroll
    for (int i = 0; i < 4; ++i)
        t32[ty + 8 * i][tx] = in[(size_t)(kb + ty + 8 * i) * N + nb + tx];
    __syncthreads();
#pragma unroll
    for (int i = 0; i < 4; ++i)
        out[(size_t)(nb + ty + 8 * i) * K + kb + tx] = f2bf(t32[tx][ty + 8 * i]);
}

// ---------------- bf16 MFMA GEMM: BK=64, XOR-swizzled LDS, XCD swizzle ------
// C[M,N] = A[M,K](bf16) @ BT[N,K](bf16)^T, fp32 accum. 1-D grid of Mt*Nt tiles.
// LDS layout: row-major [row][8 slots of 8 bf16], slot = kc8 ^ (row&7) so the
// fragment ds_read_b128s of 16 consecutive-row lanes spread over all 32 banks.
template<int HAS_BIAS, int HAS_ADD, int ADD_BF, int HAS_SCALE, int OUT_F32, int OUT_BF, int SWZ>
__global__ __launch_bounds__(256, 4) void gemm_bf16(
    const short* __restrict__ A, const short* __restrict__ BT,
    const float* __restrict__ bias,
    const float* __restrict__ addf, const short* __restrict__ addb,
    const float* __restrict__ addscale,
    float* __restrict__ Cf, short* __restrict__ Cbf,
    int Mt, int Nt, int K) {
    __shared__ short As[128 * 64];   // 16 KiB
    __shared__ short Bs[128 * 64];   // 16 KiB
    int p = blockIdx.x;
    int mtile, ntile;
    if (SWZ) {           // xcd = p&7; each XCD runs (m, n=0..7) consecutively
        int k = p & 7, q = p >> 3;
        ntile = q & 7;
        mtile = k + 8 * (q >> 3);
    } else {
        mtile = p % Mt;
        ntile = p / Mt;
    }
    int m0 = mtile * 128, n0 = ntile * 128;
    int N = Nt * 128;
    int tid = threadIdx.x;
    int lane = tid & 63;
    int w = tid >> 6;
    int quad = lane >> 4, r16 = lane & 15;
    int wm = (w & 1) * 64, wn = (w >> 1) * 64;

    f32x4 acc[4][4] = {};

    for (int k0 = 0; k0 < K; k0 += 64) {
#pragma unroll
        for (int it = 0; it < 4; ++it) {
            int seg = it * 256 + tid;          // 0..1023
            int row = seg >> 3, slot = seg & 7;
            int kc8 = slot ^ (row & 7);
            const short* gp = A + (size_t)(m0 + row) * K + k0 + kc8 * 8;
            __builtin_amdgcn_global_load_lds(
                (const __attribute__((address_space(1))) unsigned*)gp,
                (__attribute__((address_space(3))) unsigned*)(As + seg * 8), 16, 0, 0);
        }
#pragma unroll
        for (int it = 0; it < 4; ++it) {
            int seg = it * 256 + tid;
            int row = seg >> 3, slot = seg & 7;
            int kc8 = slot ^ (row & 7);
            const short* gp = BT + (size_t)(n0 + row) * K + k0 + kc8 * 8;
            __builtin_amdgcn_global_load_lds(
                (const __attribute__((address_space(1))) unsigned*)gp,
                (__attribute__((address_space(3))) unsigned*)(Bs + seg * 8), 16, 0, 0);
        }
        __syncthreads();

        const short* abase = As + (wm + r16) * 64;
        const short* bbase = Bs + (wn + r16) * 64;
        int sw = r16 & 7;
#pragma unroll
        for (int kk = 0; kk < 2; ++kk) {
            int phys = ((quad + 4 * kk) ^ sw) * 8;
            bf16x8 af[4], bfr[4];
#pragma unroll
            for (int i = 0; i < 4; ++i) af[i] = *(const bf16x8*)(abase + i * 16 * 64 + phys);
#pragma unroll
            for (int j = 0; j < 4; ++j) bfr[j] = *(const bf16x8*)(bbase + j * 16 * 64 + phys);
#pragma unroll
            for (int i = 0; i < 4; ++i)
#pragma unroll
                for (int j = 0; j < 4; ++j)
                    acc[i][j] = __builtin_amdgcn_mfma_f32_16x16x32_bf16(af[i], bfr[j], acc[i][j], 0, 0, 0);
        }
        __syncthreads();
    }

#pragma unroll
    for (int i = 0; i < 4; ++i) {
#pragma unroll
        for (int j = 0; j < 4; ++j) {
            int col = n0 + wn + j * 16 + r16;
            float bv = HAS_BIAS ? bias[col] : 0.f;
            float sc = HAS_SCALE ? addscale[col] : 1.f;
#pragma unroll
            for (int pr = 0; pr < 4; ++pr) {
                int row = m0 + wm + i * 16 + quad * 4 + pr;
                float v = acc[i][j][pr] + bv;
                if (HAS_ADD) {
                    float av = ADD_BF ? bf2f(addb[(size_t)row * N + col])
                                      : addf[(size_t)row * N + col];
                    v += sc * av;
                }
                if (OUT_F32) Cf[(size_t)row * N + col] = v;
                if (OUT_BF) Cbf[(size_t)row * N + col] = f2bf(v);
            }
        }
    }
}

// ---------------- Chunked linear scan (exact FFT-conv replacement) ----------------
__global__ __launch_bounds__(128) void scan_p1(const float* __restrict__ s3,
                                               const float* __restrict__ A_log,
                                               float* __restrict__ hbuf,
                                               float* __restrict__ Ebuf) {
    int s = threadIdx.x;
    int c = blockIdx.x, b = blockIdx.y;
    float a = expf(-expf(A_log[s]));
    float h = 0.f;
    size_t base = (size_t)b * SEQ_LEN + (size_t)c * LCHUNK;
#pragma unroll 8
    for (int i = 0; i < LCHUNK; ++i) {
        size_t r = base + i;
        float u = s3[r * 384 + s] * s3[r * 384 + 128 + s];
        h = a * h + u;
        hbuf[r * 128 + s] = h;
    }
    Ebuf[((size_t)b * NCHUNK + c) * 128 + s] = h;
}

__global__ __launch_bounds__(512) void scan_p2(const float* __restrict__ A_log,
                                               const float* __restrict__ Ebuf,
                                               float* __restrict__ Gbuf) {
    int tid = threadIdx.x;
    int b = tid >> 7, s = tid & 127;
    float pw = expf(-expf(A_log[s]) * (float)LCHUNK);
    float G = 0.f;
    for (int c0 = 0; c0 < NCHUNK; c0 += 16) {
        float e[16];
#pragma unroll
        for (int t = 0; t < 16; ++t)
            e[t] = Ebuf[((size_t)b * NCHUNK + c0 + t) * 128 + s];
#pragma unroll
        for (int t = 0; t < 16; ++t) {
            G = pw * G + e[t];
            Gbuf[((size_t)b * NCHUNK + c0 + t) * 128 + s] = G;
        }
    }
}

__global__ __launch_bounds__(128) void scan_p3(const float* __restrict__ s3,
                                               const float* __restrict__ A_log,
                                               const float* __restrict__ hbuf,
                                               const float* __restrict__ Gbuf,
                                               short* __restrict__ ys_bf) {
    int s = threadIdx.x;
    int c = blockIdx.x, b = blockIdx.y;
    float a = expf(-expf(A_log[s]));
    float carry = (c == 0) ? 0.f : Gbuf[((size_t)b * NCHUNK + c - 1) * 128 + s];
    float p = a;
    size_t base = (size_t)b * SEQ_LEN + (size_t)c * LCHUNK;
#pragma unroll 8
    for (int i = 0; i < LCHUNK; ++i) {
        size_t r = base + i;
        float h = hbuf[r * 128 + s] + p * carry;
        p *= a;
        ys_bf[r * 128 + s] = f2bf(h * s3[r * 384 + 256 + s]);
    }
}

extern "C" void kernel_launch(void* const* d_in, const int* in_sizes, int n_in,
                              void* d_out, int out_size, void* d_ws, size_t ws_size,
                              hipStream_t stream) {
    const float* x     = (const float*)d_in[0];
    const float* ln_g  = (const float*)d_in[1];
    const float* ln_b  = (const float*)d_in[2];
    const float* W_in  = (const float*)d_in[3];
    const float* b_in  = (const float*)d_in[4];
    const float* W_xs  = (const float*)d_in[5];
    const float* W_B   = (const float*)d_in[6];
    const float* b_B   = (const float*)d_in[7];
    const float* W_C   = (const float*)d_in[8];
    const float* b_C   = (const float*)d_in[9];
    const float* A_log = (const float*)d_in[10];
    const float* Dvec  = (const float*)d_in[11];
    const float* W_so  = (const float*)d_in[12];
    const float* W_out = (const float*)d_in[13];
    const float* b_out = (const float*)d_in[14];
    float* out = (float*)d_out;

    // ---- workspace carve (bytes) ----
    char* w = (char*)d_ws;
    size_t off = 0;
    short* xn_bf = (short*)(w + off);                       // region 0: 32 MiB
    float* hbuf  = (float*)(w + off);                       //   reuses region 0 after GEMM1
    short* ys_bf = (short*)(w + off + 8388608);             //   after hbuf (8 MiB)
    off += (size_t)NTOK * D_MODEL * 2;
    short* z_bf  = (short*)(w + off);                       // region 1: 32 MiB
    off += (size_t)NTOK * D_MODEL * 2;
    short* y1_bf = (short*)(w + off);                       // region 2: 32 MiB
    off += (size_t)NTOK * D_MODEL * 2;
    float* s3    = (float*)(w + off); off += (size_t)NTOK * 384 * 4;       // 24 MiB
    float* Ebuf  = (float*)(w + off); off += (size_t)BATCH * NCHUNK * 128 * 4;
    float* Gbuf  = (float*)(w + off); off += (size_t)BATCH * NCHUNK * 128 * 4;
    short* W_inT  = (short*)(w + off); off += (size_t)D_MODEL * D_MODEL * 2;
    short* W3T    = (short*)(w + off); off += (size_t)384 * D_MODEL * 2;
    short* W_soT  = (short*)(w + off); off += (size_t)D_MODEL * D_STATE * 2;
    short* W_outT = (short*)(w + off); off += (size_t)D_MODEL * D_MODEL * 2;
    float* bias3  = (float*)(w + off); off += 2048;

    // ---- weight prep (single launch) ----
    prep_kernel<<<2561, dim3(32, 8), 0, stream>>>(W_in, W_xs, W_B, W_C, W_so, W_out,
                                                  b_B, b_C, W_inT, W3T, W_soT, W_outT, bias3);

    // ---- 1) LayerNorm -> bf16 ----
    ln_kernel<<<NTOK, 256, 0, stream>>>(x, ln_g, ln_b, xn_bf);

    const int Mt = NTOK / 128;   // 128
    // ---- 2) z = xn @ W_in + b_in  (bf16) ----
    gemm_bf16<1, 0, 0, 0, 0, 1, 1><<<Mt * 8, 256, 0, stream>>>(
        xn_bf, W_inT, b_in, nullptr, nullptr, nullptr,
        nullptr, z_bf, Mt, 8, D_MODEL);

    // ---- 3) s3 = z @ [W_xs|W_B|W_C] + bias3  (f32) ----
    gemm_bf16<1, 0, 0, 0, 1, 0, 0><<<Mt * 3, 256, 0, stream>>>(
        z_bf, W3T, bias3, nullptr, nullptr, nullptr,
        s3, nullptr, Mt, 3, D_MODEL);

    // ---- 4) chunked scan (fp32 exact), fused *C_sel -> ys_bf ----
    scan_p1<<<dim3(NCHUNK, BATCH), 128, 0, stream>>>(s3, A_log, hbuf, Ebuf);
    scan_p2<<<1, 512, 0, stream>>>(A_log, Ebuf, Gbuf);
    scan_p3<<<dim3(NCHUNK, BATCH), 128, 0, stream>>>(s3, A_log, hbuf, Gbuf, ys_bf);

    // ---- 5) y1 = ys @ W_so + D*z  (bf16 out, bf16 addmat) ----
    gemm_bf16<0, 1, 1, 1, 0, 1, 1><<<Mt * 8, 256, 0, stream>>>(
        ys_bf, W_soT, nullptr, nullptr, z_bf, Dvec,
        nullptr, y1_bf, Mt, 8, D_STATE);

    // ---- 6) out = y1 @ W_out + b_out + x (f32 residual) ----
    gemm_bf16<1, 1, 0, 0, 1, 0, 1><<<Mt * 8, 256, 0, stream>>>(
        y1_bf, W_outT, b_out, x, nullptr, nullptr,
        out, nullptr, Mt, 8, D_MODEL);
}